// Round 8
// baseline (127.105 us; speedup 1.0000x reference)
//
#include <hip/hip_runtime.h>

// _GSPostProcessor: out = D^{-1/2} (topk20(relu(A) + dope*1e-4)*relu(A) + I) D^{-1/2}
// B=16, N=2048, K=20.
// R8 = R7 numerics/structure + dispatch/MLP restructure:
//  topk_pair : wave handles 2 rows; 16 NT f32x4 loads in flight; push both rows to
//              LDS candidate slots, sort both (data regs die), THEN guard/redo/emit
//              per row (rare exact doped redo inline, R1-proven path).
//  scatter_gs: grid-stride block-per-8-rows register-compose scatter, NT stores
//              (same additive formula as the absmax=0.0-proven scatter).

static constexpr int N    = 2048;
static constexpr int KSEL = 20;
static constexpr int NR   = 16 * 2048;   // B*N rows

typedef unsigned int uint2v __attribute__((ext_vector_type(2)));
typedef float f32x4 __attribute__((ext_vector_type(4)));

#if __has_builtin(__builtin_nontemporal_load)
#define NT_LOAD(p) __builtin_nontemporal_load(p)
#else
#define NT_LOAD(p) (*(p))
#endif
#if __has_builtin(__builtin_nontemporal_store)
#define NT_STORE(v, p) __builtin_nontemporal_store((v), (p))
#else
#define NT_STORE(v, p) (*(p) = (v))
#endif

// ---------------- cross-lane primitives ----------------
#if __has_builtin(__builtin_amdgcn_mov_dpp)
#define XD(v, ctrl) ((unsigned)__builtin_amdgcn_mov_dpp((int)(v), (ctrl), 0xF, 0xF, false))
#else
#define XD(v, ctrl) ((unsigned)__shfl_xor((int)(v), ((ctrl) == 0xB1 ? 1 : 2)))
#endif
#if __has_builtin(__builtin_amdgcn_ds_swizzle)
#define XS(v, imm) ((unsigned)__builtin_amdgcn_ds_swizzle((int)(v), (imm)))
#else
#define XS(v, imm) ((unsigned)__shfl_xor((int)(v), (((imm) >> 10) & 0x1F)))
#endif

__device__ __forceinline__ unsigned read_lane_u32(unsigned v, int srclane) {
#if __has_builtin(__builtin_amdgcn_readlane)
  return (unsigned)__builtin_amdgcn_readlane((int)v, srclane);
#else
  return (unsigned)__shfl((int)v, srclane, 64);
#endif
}

// compare-exchange: {A,B} = {self, partner} (order irrelevant); keep max iff km.
__device__ __forceinline__ void cex(unsigned& hi, unsigned& lo,
                                    unsigned Ahi, unsigned Alo,
                                    unsigned Bhi, unsigned Blo, bool km) {
  unsigned long long Av = ((unsigned long long)Ahi << 32) | Alo;
  unsigned long long Bv = ((unsigned long long)Bhi << 32) | Blo;
  bool sel = (km == (Av > Bv));
  hi = sel ? Ahi : Bhi;
  lo = sel ? Alo : Blo;
}

#define KM(K2, J) ((((lane & (J)) == 0)) != (((lane & (K2)) != 0)))
#define EX1(K2)  cex(hi, lo, hi, lo, XD(hi, 0xB1), XD(lo, 0xB1), KM(K2, 1))
#define EX2(K2)  cex(hi, lo, hi, lo, XD(hi, 0x4E), XD(lo, 0x4E), KM(K2, 2))
#define EX4(K2)  cex(hi, lo, hi, lo, XS(hi, 0x101F), XS(lo, 0x101F), KM(K2, 4))
#define EX8(K2)  cex(hi, lo, hi, lo, XS(hi, 0x201F), XS(lo, 0x201F), KM(K2, 8))
#if __has_builtin(__builtin_amdgcn_permlane16_swap)
#define EX16(K2) { uint2v r_ = __builtin_amdgcn_permlane16_swap(hi, hi, false, false); \
                   uint2v s_ = __builtin_amdgcn_permlane16_swap(lo, lo, false, false); \
                   cex(hi, lo, (unsigned)r_[0], (unsigned)s_[0], (unsigned)r_[1], (unsigned)s_[1], KM(K2, 16)); }
#else
#define EX16(K2) cex(hi, lo, hi, lo, (unsigned)__shfl_xor((int)hi, 16), (unsigned)__shfl_xor((int)lo, 16), KM(K2, 16))
#endif
#if __has_builtin(__builtin_amdgcn_permlane32_swap)
#define EX32(K2) { uint2v r_ = __builtin_amdgcn_permlane32_swap(hi, hi, false, false); \
                   uint2v s_ = __builtin_amdgcn_permlane32_swap(lo, lo, false, false); \
                   cex(hi, lo, (unsigned)r_[0], (unsigned)s_[0], (unsigned)r_[1], (unsigned)s_[1], KM(K2, 32)); }
#else
#define EX32(K2) cex(hi, lo, hi, lo, (unsigned)__shfl_xor((int)hi, 32), (unsigned)__shfl_xor((int)lo, 32), KM(K2, 32))
#endif

#define SORT64() do {                                     \
    EX1(2);                                               \
    EX2(4);  EX1(4);                                      \
    EX4(8);  EX2(8);  EX1(8);                             \
    EX8(16); EX4(16); EX2(16); EX1(16);                   \
    EX16(32); EX8(32); EX4(32); EX2(32); EX1(32);         \
    EX32(64); EX16(64); EX8(64); EX4(64); EX2(64); EX1(64); \
  } while (0)

// ---------------- exact (R1-proven) doped path ----------------
__device__ __forceinline__ void ins4(float vc, int jc,
                                     float& t0, float& t1, float& t2, float& t3,
                                     int& j0, int& j1, int& j2, int& j3) {
  bool b0 = vc > t0;
  float d0 = b0 ? t0 : vc; int e0 = b0 ? j0 : jc;
  t0 = b0 ? vc : t0;       j0 = b0 ? jc : j0;
  bool b1 = d0 > t1;
  float d1 = b1 ? t1 : d0; int e1 = b1 ? j1 : e0;
  t1 = b1 ? d0 : t1;       j1 = b1 ? e0 : j1;
  bool b2 = d1 > t2;
  float d2 = b2 ? t2 : d1; int e2 = b2 ? j2 : e1;
  t2 = b2 ? d1 : t2;       j2 = b2 ? e1 : j2;
  bool b3 = d2 > t3;
  t3 = b3 ? d2 : t3;       j3 = b3 ? e2 : j3;
}

__device__ __forceinline__ int wave_topk_exact(const float* __restrict__ Arow,
                                               const float* __restrict__ Drow,
                                               int lane) {
  float v[32];
  const float4* A4 = reinterpret_cast<const float4*>(Arow);
  const float4* D4 = reinterpret_cast<const float4*>(Drow);
#pragma unroll
  for (int c4 = 0; c4 < 8; ++c4) {
    float4 a = A4[c4 * 64 + lane];
    float4 d = D4[c4 * 64 + lane];
    v[c4 * 4 + 0] = __fadd_rn(fmaxf(a.x, 0.0f), __fmul_rn(d.x, 1e-4f));
    v[c4 * 4 + 1] = __fadd_rn(fmaxf(a.y, 0.0f), __fmul_rn(d.y, 1e-4f));
    v[c4 * 4 + 2] = __fadd_rn(fmaxf(a.z, 0.0f), __fmul_rn(d.z, 1e-4f));
    v[c4 * 4 + 3] = __fadd_rn(fmaxf(a.w, 0.0f), __fmul_rn(d.w, 1e-4f));
  }
  float t0 = -1.f, t1 = -1.f, t2 = -1.f, t3 = -1.f;
  int   j0 = 0,    j1 = 0,    j2 = 0,    j3 = 0;
#pragma unroll
  for (int c = 0; c < 32; ++c) {
    int jc = ((c >> 2) << 8) | (lane << 2) | (c & 3);
    ins4(v[c], jc, t0, t1, t2, t3, j0, j1, j2, j3);
  }
  unsigned consumed = 0;
  int jmine = 0;
#pragma unroll 1
  for (int it = 0; it < KSEL; ++it) {
    if (__any(t0 < 0.0f)) {
      if (t0 < 0.0f) {
        t0 = t1 = t2 = t3 = -1.f; j0 = j1 = j2 = j3 = 0;
#pragma unroll
        for (int c = 0; c < 32; ++c) {
          float vc = ((consumed >> c) & 1u) ? -1.0f : v[c];
          int jc = ((c >> 2) << 8) | (lane << 2) | (c & 3);
          ins4(vc, jc, t0, t1, t2, t3, j0, j1, j2, j3);
        }
      }
    }
    float m = t0;
#pragma unroll
    for (int off = 32; off; off >>= 1) m = fmaxf(m, __shfl_xor(m, off));
    int cj = (t0 == m) ? j0 : 0x7fffffff;
#pragma unroll
    for (int off = 32; off; off >>= 1) cj = min(cj, __shfl_xor(cj, off));
    if (lane == it) jmine = cj;
    if (((cj >> 2) & 63) == lane) {
      int c = ((cj >> 8) << 2) | (cj & 3);
      consumed |= (1u << c);
      t0 = t1; j0 = j1; t1 = t2; j1 = j2; t2 = t3; j2 = j3; t3 = -1.f; j3 = 0;
    }
  }
  return jmine;
}

// guard + (rare) exact redo + emit for one row; hi/lo/cnt from the A-only sort.
__device__ __forceinline__ void finish_row(const float* __restrict__ A,
                                           const float* __restrict__ D,
                                           int r, unsigned hi, unsigned lo,
                                           unsigned cnt, int lane,
                                           float* __restrict__ wval,
                                           int* __restrict__ widx,
                                           float* __restrict__ wdinv) {
  const float T = 2.05f;
  size_t base = (size_t)r * N;
  // Set-exactness guard: doped keys shift by at most +1e-4 (exact fp32 bound).
  float a19 = __uint_as_float(read_lane_u32(hi, 19));
  float a20 = __uint_as_float(read_lane_u32(hi, 20));
  bool decided = (a19 > __fadd_rn(a20, 1e-4f)) && (a19 > __fadd_rn(T, 1e-4f));
  bool bad = (cnt < (unsigned)KSEL) || (cnt > 64u) || !decided;  // wave-uniform

  int jsel = 2047 - (int)lo;
  float val = (lane < KSEL) ? __uint_as_float(hi) : 0.0f;  // sorted key IS relu(a)

  if (bad) {                    // ~0.3% of waves: exact doped redo
    int jm = wave_topk_exact(A + base, D + base, lane);
    jsel = jm;
    val = (lane < KSEL) ? fmaxf(A[base + jm], 0.0f) : 0.0f;
  }

  float s = val;
#pragma unroll
  for (int off = 32; off; off >>= 1) s += __shfl_xor(s, off);
  float dinv = (float)(1.0 / sqrt(1.0 + (double)s));       // row sum >= 1, never inf

  if (lane < KSEL) {
    wval[r * KSEL + lane] = val;
    widx[r * KSEL + lane] = jsel;
  }
  if (lane == 0) wdinv[r] = dinv;
}

// ---------------- pass 1: 2 rows per wave, 16 NT loads in flight ----------------
__global__ void __launch_bounds__(256)
topk_pair(const float* __restrict__ A, const float* __restrict__ D,
          float* __restrict__ wval, int* __restrict__ widx,
          float* __restrict__ wdinv) {
  __shared__ unsigned long long cand[4][2][64];
  __shared__ unsigned scnt[4][2];
  const float T = 2.05f;
  int lane = threadIdx.x & 63;
  int w = threadIdx.x >> 6;
  int gw = blockIdx.x * 4 + w;
  int r0 = gw * 2, r1 = r0 + 1;
  const f32x4* A40 = reinterpret_cast<const f32x4*>(A + (size_t)r0 * N);
  const f32x4* A41 = reinterpret_cast<const f32x4*>(A + (size_t)r1 * N);

  // 16 independent NT loads in flight
  f32x4 a0 = NT_LOAD(A40 + lane);       f32x4 a1 = NT_LOAD(A40 + 64 + lane);
  f32x4 a2 = NT_LOAD(A40 + 128 + lane); f32x4 a3 = NT_LOAD(A40 + 192 + lane);
  f32x4 a4 = NT_LOAD(A40 + 256 + lane); f32x4 a5 = NT_LOAD(A40 + 320 + lane);
  f32x4 a6 = NT_LOAD(A40 + 384 + lane); f32x4 a7 = NT_LOAD(A40 + 448 + lane);
  f32x4 b0 = NT_LOAD(A41 + lane);       f32x4 b1 = NT_LOAD(A41 + 64 + lane);
  f32x4 b2 = NT_LOAD(A41 + 128 + lane); f32x4 b3 = NT_LOAD(A41 + 192 + lane);
  f32x4 b4 = NT_LOAD(A41 + 256 + lane); f32x4 b5 = NT_LOAD(A41 + 320 + lane);
  f32x4 b6 = NT_LOAD(A41 + 384 + lane); f32x4 b7 = NT_LOAD(A41 + 448 + lane);

  cand[w][0][lane] = 0ull;     // padding sorts to the bottom (real keys > T > 0)
  cand[w][1][lane] = 0ull;
  if (lane == 0) { scnt[w][0] = 0u; scnt[w][1] = 0u; }

#define PUSH1(ROW, AV, J) do {                                                 \
    float k_ = fmaxf((AV), 0.0f);                                              \
    if (k_ > T) {                                                              \
      unsigned p_ = atomicAdd(&scnt[w][ROW], 1u);                              \
      if (p_ < 64u)                                                            \
        cand[w][ROW][p_] = ((unsigned long long)__float_as_uint(k_) << 32) |   \
                           (unsigned)(2047 - (J));                             \
    }                                                                          \
  } while (0)
#define PUSH4(ROW, AA, C4) do {                                                \
    int jb_ = ((C4) << 8) | (lane << 2);                                       \
    PUSH1(ROW, AA.x, jb_ + 0);                                                 \
    PUSH1(ROW, AA.y, jb_ + 1);                                                 \
    PUSH1(ROW, AA.z, jb_ + 2);                                                 \
    PUSH1(ROW, AA.w, jb_ + 3);                                                 \
  } while (0)

  PUSH4(0, a0, 0); PUSH4(0, a1, 1); PUSH4(0, a2, 2); PUSH4(0, a3, 3);
  PUSH4(0, a4, 4); PUSH4(0, a5, 5); PUSH4(0, a6, 6); PUSH4(0, a7, 7);
  PUSH4(1, b0, 0); PUSH4(1, b1, 1); PUSH4(1, b2, 2); PUSH4(1, b3, 3);
  PUSH4(1, b4, 4); PUSH4(1, b5, 5); PUSH4(1, b6, 6); PUSH4(1, b7, 7);
#undef PUSH4
#undef PUSH1

  // wave-private LDS; drain DS pipe before cross-lane reads
  __asm__ __volatile__("s_waitcnt lgkmcnt(0)" ::: "memory");
  unsigned cnt0 = scnt[w][0], cnt1 = scnt[w][1];
  unsigned long long kv0 = cand[w][0][lane];
  unsigned long long kv1 = cand[w][1][lane];

  // sort both rows first so the 64 data VGPRs are dead before any rare redo
  unsigned hi, lo;
  hi = (unsigned)(kv0 >> 32); lo = (unsigned)kv0;
  SORT64();
  unsigned hi0 = hi, lo0 = lo;
  hi = (unsigned)(kv1 >> 32); lo = (unsigned)kv1;
  SORT64();
  unsigned hi1 = hi, lo1 = lo;

  finish_row(A, D, r0, hi0, lo0, cnt0, lane, wval, widx, wdinv);
  finish_row(A, D, r1, hi1, lo1, cnt1, lane, wval, widx, wdinv);
}

// ---------------- pass 2: grid-stride register-compose scatter (NT stores) ----------------
__global__ void __launch_bounds__(256)
scatter_gs(const float* __restrict__ wval, const int* __restrict__ widx,
           const float* __restrict__ wdinv, float* __restrict__ out) {
  int tid = threadIdx.x;
#pragma unroll 1
  for (int k = 0; k < 8; ++k) {
    int r = blockIdx.x * 8 + k;
    int i = r & (N - 1);
    int bb = r & ~(N - 1);               // batch row-base
    float di = wdinv[r];

    float v0 = 0.f, v1 = 0.f, v2 = 0.f, v3 = 0.f,
          v4 = 0.f, v5 = 0.f, v6 = 0.f, v7 = 0.f;
    if ((i & 255) == tid) {
      float dd = di * di;
      switch (i >> 8) {
        case 0: v0 = dd; break; case 1: v1 = dd; break;
        case 2: v2 = dd; break; case 3: v3 = dd; break;
        case 4: v4 = dd; break; case 5: v5 = dd; break;
        case 6: v6 = dd; break; case 7: v7 = dd; break;
      }
    }
#pragma unroll
    for (int t = 0; t < KSEL; ++t) {
      int j = widx[r * KSEL + t];        // uniform -> scalar load
      if ((j & 255) == tid) {            // <=20 of 256 threads hit
        float c = di * wval[r * KSEL + t] * wdinv[bb + j];
        switch (j >> 8) {
          case 0: v0 += c; break; case 1: v1 += c; break;
          case 2: v2 += c; break; case 3: v3 += c; break;
          case 4: v4 += c; break; case 5: v5 += c; break;
          case 6: v6 += c; break; case 7: v7 += c; break;
        }
      }
    }
    float* o = out + (size_t)r * N;
    NT_STORE(v0, o + tid);         NT_STORE(v1, o + 256 + tid);
    NT_STORE(v2, o + 512 + tid);   NT_STORE(v3, o + 768 + tid);
    NT_STORE(v4, o + 1024 + tid);  NT_STORE(v5, o + 1280 + tid);
    NT_STORE(v6, o + 1536 + tid);  NT_STORE(v7, o + 1792 + tid);
  }
}

// ---------------- fallback (tiny ws): exact fused path, R1-proven ----------------
__global__ void __launch_bounds__(256)
topk_exact_pass1(const float* __restrict__ A, const float* __restrict__ D,
                 float* __restrict__ wdinv) {
  int lane = threadIdx.x & 63;
  int r = blockIdx.x * 4 + (threadIdx.x >> 6);
  size_t base = (size_t)r * N;
  int jm = wave_topk_exact(A + base, D + base, lane);
  float val = 0.0f;
  if (lane < KSEL) val = fmaxf(A[base + jm], 0.0f);
  float s = (lane < KSEL) ? val : 0.0f;
#pragma unroll
  for (int off = 32; off; off >>= 1) s += __shfl_xor(s, off);
  float dinv = (float)(1.0 / sqrt(1.0 + (double)s));
  if (lane == 0) wdinv[r] = dinv;
}

__global__ void __launch_bounds__(256)
fallback_pass2(const float* __restrict__ A, const float* __restrict__ D,
               const float* __restrict__ wdinv, float* __restrict__ out) {
  __shared__ float rows[4][N];
  int lane = threadIdx.x & 63;
  int w = threadIdx.x >> 6;
  int r = blockIdx.x * 4 + w;
  size_t base = (size_t)r * N;
  int i = r & (N - 1);
  int jm = wave_topk_exact(A + base, D + base, lane);
  float val = 0.0f;
  if (lane < KSEL) val = fmaxf(A[base + jm], 0.0f);
  float s = (lane < KSEL) ? val : 0.0f;
#pragma unroll
  for (int off = 32; off; off >>= 1) s += __shfl_xor(s, off);
  float di = (float)(1.0 / sqrt(1.0 + (double)s));
  float4* rv = reinterpret_cast<float4*>(rows[w]);
  float4 z = make_float4(0.f, 0.f, 0.f, 0.f);
#pragma unroll
  for (int q = 0; q < 8; ++q) rv[q * 64 + lane] = z;
  __syncthreads();
  if (lane < KSEL) {
    float dj = wdinv[(r & ~(N - 1)) + jm];
    atomicAdd(&rows[w][jm], di * val * dj);
  } else if (lane == KSEL) {
    atomicAdd(&rows[w][i], di * di);
  }
  __syncthreads();
  float4* o4 = reinterpret_cast<float4*>(out + base);
#pragma unroll
  for (int q = 0; q < 8; ++q) o4[q * 64 + lane] = rv[q * 64 + lane];
}

extern "C" void kernel_launch(void* const* d_in, const int* in_sizes, int n_in,
                              void* d_out, int out_size, void* d_ws, size_t ws_size,
                              hipStream_t stream) {
  const float* A = (const float*)d_in[0];
  const float* D = (const float*)d_in[1];
  float* out = (float*)d_out;
  char* ws = (char*)d_ws;
  size_t off_val  = 0;
  size_t off_idx  = off_val + (size_t)NR * KSEL * sizeof(float);
  size_t off_dinv = off_idx + (size_t)NR * KSEL * sizeof(int);
  size_t total    = off_dinv + (size_t)NR * sizeof(float);
  if (ws_size >= total) {
    float* wval  = (float*)(ws + off_val);
    int*   widx  = (int*)(ws + off_idx);
    float* wdinv = (float*)(ws + off_dinv);
    topk_pair<<<NR / 8, 256, 0, stream>>>(A, D, wval, widx, wdinv);
    scatter_gs<<<NR / 8, 256, 0, stream>>>(wval, widx, wdinv, out);
  } else {
    float* wdinv = (float*)ws;
    topk_exact_pass1<<<NR / 4, 256, 0, stream>>>(A, D, wdinv);
    fallback_pass2<<<NR / 4, 256, 0, stream>>>(A, D, wdinv, out);
  }
}